// Round 6
// baseline (1317.423 us; speedup 1.0000x reference)
//
#include <hip/hip_runtime.h>
#include <hip/hip_bf16.h>

#define L_    4096
#define DIN   512
#define DOUT  256
#define NH    4
#define HD    64

typedef unsigned short u16;

__device__ __forceinline__ float bf2f(u16 u) {
  union { unsigned u32; float f; } v; v.u32 = ((unsigned)u) << 16; return v.f;
}
__device__ __forceinline__ u16 f2bf(float f) {  // RNE
  union { float f; unsigned u; } v; v.f = f;
  unsigned r = v.u + 0x7fff + ((v.u >> 16) & 1);
  return (u16)(r >> 16);
}
__device__ __forceinline__ float q16(float f) {  // bf16 round-trip (mimic MFMA input quant)
  return bf2f(f2bf(f));
}

// ---------------------------------------------------------------------------
// K1 SCALAR: identical structure/epilogue to the MFMA k1, but the inner
// product is a scalar FMA loop computing the exact values acc[nt][r] that the
// MFMA was assumed to produce (thread (w,lane): rows i0+q*4+r, cols
// w*64+nt*16+c0). Inputs bf16-quantized so the ONLY delta vs the MFMA
// version is the MFMA instruction itself.
// ---------------------------------------------------------------------------
__global__ __launch_bounds__(256) void k1_scalar(
    const float* __restrict__ h, const float* __restrict__ W,
    const float* __restrict__ attn,
    u16* __restrict__ WhT, float* __restrict__ s1g, float* __restrict__ s2g)
{
  const int i0 = blockIdx.x * 16;
  const int t = threadIdx.x;
  const int w = t >> 6, lane = t & 63, q = lane >> 4, c0 = lane & 15;

  float acc[4][4] = {};   // [nt][r]
  for (int kb = 0; kb < DIN; kb += 4) {
    float4 hv[4];
    #pragma unroll
    for (int r = 0; r < 4; ++r)
      hv[r] = *(const float4*)(h + (size_t)(i0 + q * 4 + r) * DIN + kb);
    #pragma unroll
    for (int nt = 0; nt < 4; ++nt) {
      const int col = w * 64 + nt * 16 + c0;
      float4 wv = *(const float4*)(W + (size_t)col * DIN + kb);
      const float w0 = q16(wv.x), w1 = q16(wv.y), w2 = q16(wv.z), w3 = q16(wv.w);
      #pragma unroll
      for (int r = 0; r < 4; ++r)
        acc[nt][r] += q16(hv[r].x) * w0 + q16(hv[r].y) * w1
                    + q16(hv[r].z) * w2 + q16(hv[r].w) * w3;
    }
  }

  // ---- epilogue identical to the MFMA k1 ----
  __shared__ float Ct[16][DOUT + 4];
  #pragma unroll
  for (int nt = 0; nt < 4; ++nt)
    #pragma unroll
    for (int r = 0; r < 4; ++r)
      Ct[q * 4 + r][w * 64 + nt * 16 + c0] = acc[nt][r];
  __syncthreads();

  if (t < 64) {  // 16 rows x 4 heads -> s1, s2 (fp32)
    const int r = t & 15, hh = t >> 4;
    float s1 = 0.f, s2 = 0.f;
    for (int d = 0; d < HD; ++d) {
      float v = Ct[r][hh * 64 + d];
      s1 += v * attn[hh * 128 + d];
      s2 += v * attn[hh * 128 + 64 + d];
    }
    s1g[hh * L_ + i0 + r] = s1;
    s2g[hh * L_ + i0 + r] = s2;
  }

  {  // WhT store: thread t = column c, 16 contiguous bf16
    const int c = t;
    union { u16 u[8]; int4 v; } p0, p1;
    #pragma unroll
    for (int r = 0; r < 8; ++r) p0.u[r] = f2bf(Ct[r][c]);
    #pragma unroll
    for (int r = 0; r < 8; ++r) p1.u[r] = f2bf(Ct[r + 8][c]);
    *(int4*)(WhT + (size_t)c * L_ + i0)     = p0.v;
    *(int4*)(WhT + (size_t)c * L_ + i0 + 8) = p1.v;
  }
}

// ---------------------------------------------------------------------------
// K2 SCALAR (unchanged from round 5): one block per i-row, fp32 VALU only.
// ---------------------------------------------------------------------------
__global__ __launch_bounds__(256) void k2_scalar(
    const int* __restrict__ A, const u16* __restrict__ WhT,
    const float* __restrict__ s1g, const float* __restrict__ s2g,
    const float* __restrict__ out_w, const float* __restrict__ out_b,
    float* __restrict__ out)
{
  const int i = blockIdx.x;
  const int t = threadIdx.x;

  __shared__ float exL[L_];
  __shared__ float red[256];
  __shared__ float CnL[DOUT];
  __shared__ float rcpS;

  const int* Arow = A + (size_t)i * L_;

  for (int hh = 0; hh < NH; ++hh) {
    const float s1v = s1g[hh * L_ + i];
    const float* s2h = s2g + (size_t)hh * L_;

    float part = 0.f;
    for (int j = t; j < L_; j += 256) {
      float e = s1v + s2h[j];
      e = fmaxf(e, 0.2f * e);                      // leaky_relu 0.2
      float ex = (Arow[j] > 0) ? __expf(e) : 0.f;  // mask = (A > 0)
      exL[j] = ex;
      part += ex;
    }
    red[t] = part;
    __syncthreads();
    for (int s = 128; s > 0; s >>= 1) {
      if (t < s) red[t] += red[t + s];
      __syncthreads();
    }
    if (t == 0) rcpS = (red[0] > 0.f) ? (1.f / red[0]) : 0.f;
    __syncthreads();
    const float rcp = rcpS;

    const int d = t & 63, sl = t >> 6;
    const u16* wrow = WhT + (size_t)(hh * HD + d) * L_;
    float a = 0.f;
    for (int j = sl * 1024; j < sl * 1024 + 1024; ++j)
      a += exL[j] * bf2f(wrow[j]);
    __syncthreads();
    red[t] = a;
    __syncthreads();
    if (t < 64)
      CnL[hh * HD + t] = (red[t] + red[64 + t] + red[128 + t] + red[192 + t]) * rcp;
    __syncthreads();
  }

  {
    const int c = t;
    const float* wr = out_w + (size_t)c * DOUT;
    float o = out_b[c];
    for (int k = 0; k < DOUT; ++k) o += CnL[k] * wr[k];
    out[(size_t)i * DOUT + c] = o;
  }
}

// ---------------------------------------------------------------------------
extern "C" void kernel_launch(void* const* d_in, const int* in_sizes, int n_in,
                              void* d_out, int out_size, void* d_ws, size_t ws_size,
                              hipStream_t stream) {
  const float* h     = (const float*)d_in[0];   // (4096, 512) fp32
  const int*   A     = (const int*)d_in[1];     // (4096, 4096) int32
  const float* W     = (const float*)d_in[2];   // (256, 512) fp32
  const float* attn  = (const float*)d_in[3];   // (4, 128) fp32
  const float* out_w = (const float*)d_in[4];   // (256, 256) fp32
  const float* out_b = (const float*)d_in[5];   // (256,) fp32
  float* outp = (float*)d_out;                  // (4096, 256) fp32

  // ws layout: WhT bf16 [256][4096] | s1 f32 [4][4096] | s2 f32 [4][4096]
  u16*   WhT = (u16*)d_ws;
  float* s1g = (float*)((char*)d_ws + (size_t)DOUT * L_ * 2);
  float* s2g = s1g + NH * L_;

  hipLaunchKernelGGL(k1_scalar, dim3(L_ / 16), dim3(256), 0, stream,
                     h, W, attn, WhT, s1g, s2g);
  hipLaunchKernelGGL(k2_scalar, dim3(L_), dim3(256), 0, stream,
                     A, WhT, s1g, s2g, out_w, out_b, outp);
}